// Round 1
// baseline (71.319 us; speedup 1.0000x reference)
//
#include <hip/hip_runtime.h>
#include <hip/hip_bf16.h>

// Decoder: preds[s,b] = hidden[s,b,:] @ W[0] + b[0]  (S=4096, B=64, H=256)
// loss = sum((preds - outputs.T)^2); d_out = [loss, preds.reshape(-1)]
//
// Memory-bound: hidden = 256 MiB f32 read once. Wave-per-row GEMV:
// 64 lanes x float4 = 256 floats = 1 KiB coalesced per row.

constexpr int S = 4096;
constexpr int B = 64;
constexpr int H = 256;
constexpr int P = S * B;          // 262144 pred rows
constexpr int BLOCK = 256;        // 4 waves/block
constexpr int GRID = 2048;        // 8192 waves -> 32 rows/wave

__global__ __launch_bounds__(BLOCK) void decoder_kernel(
    const float* __restrict__ outputs,   // [B, S]
    const float* __restrict__ hidden,    // [S, B, H]
    const float* __restrict__ W,         // [1, H]
    const float* __restrict__ bias,      // [1]
    float* __restrict__ out)             // [1 + P]: out[0]=loss, out[1+p]=pred
{
    const int lane = threadIdx.x & 63;
    const int gwave = (blockIdx.x * BLOCK + threadIdx.x) >> 6;
    const int nwaves = (GRID * BLOCK) >> 6;  // 8192

    // Each lane owns 4 consecutive W elements (lane*4 .. lane*4+3).
    const float4 w4 = reinterpret_cast<const float4*>(W)[lane];
    const float b0 = bias[0];

    float se_acc = 0.0f;

    for (int p = gwave; p < P; p += nwaves) {
        const float4 h4 =
            reinterpret_cast<const float4*>(hidden + (size_t)p * H)[lane];
        float d = h4.x * w4.x + h4.y * w4.y + h4.z * w4.z + h4.w * w4.w;
        // 64-lane butterfly reduction
        #pragma unroll
        for (int off = 32; off > 0; off >>= 1)
            d += __shfl_xor(d, off, 64);
        const float pred = d + b0;
        if (lane == 0) {
            out[1 + p] = pred;
            const int s = p >> 6;      // p = s*B + b, B=64
            const int bb = p & 63;
            const float diff = pred - outputs[bb * S + s];
            se_acc += diff * diff;
        }
    }

    // Block-level loss reduction: 4 wave-lane0 partials -> 1 atomic per block.
    __shared__ float lsum[BLOCK / 64];
    if (lane == 0) lsum[threadIdx.x >> 6] = se_acc;
    __syncthreads();
    if (threadIdx.x == 0) {
        atomicAdd(out, lsum[0] + lsum[1] + lsum[2] + lsum[3]);
    }
}

extern "C" void kernel_launch(void* const* d_in, const int* in_sizes, int n_in,
                              void* d_out, int out_size, void* d_ws, size_t ws_size,
                              hipStream_t stream) {
    const float* outputs = (const float*)d_in[0];  // [B, S]
    const float* hidden  = (const float*)d_in[1];  // [S, B, H]
    const float* W       = (const float*)d_in[2];  // [1, H]
    const float* bias    = (const float*)d_in[3];  // [1]
    float* out = (float*)d_out;                    // [1 + S*B]

    // Atomic accumulator must start at 0 every call (harness doesn't re-poison).
    hipMemsetAsync(out, 0, sizeof(float), stream);

    decoder_kernel<<<GRID, BLOCK, 0, stream>>>(outputs, hidden, W, bias, out);
}

// Round 2
// 60.914 us; speedup vs baseline: 1.1708x; 1.1708x over previous
//
#include <hip/hip_runtime.h>
#include <hip/hip_bf16.h>

// Decoder: preds[s,b] = hidden[s,b,:] @ W[0] + b[0]  (S=4096, B=64, H=256)
// loss = sum((preds - outputs.T)^2); d_out = [loss, preds.reshape(-1)]
//
// Memory-bound: hidden = 256 MiB f32 read once -> HBM floor ~41 us.
// R1 layout: 16 lanes per row, 16 floats (4x float4) per lane.
// A wave covers 4 rows/iter (4 KiB), reduction = 4 shuffle steps per row
// (vs 6 per row in wave-per-row), 4 independent load chains per iter.

constexpr int S = 4096;
constexpr int B = 64;
constexpr int H = 256;
constexpr int P = S * B;          // 262144 pred rows
constexpr int BLOCK = 256;        // 4 waves/block
constexpr int GRID = 2048;        // 8192 waves; 4 rows/wave/iter -> 8 iters

__global__ __launch_bounds__(BLOCK) void decoder_kernel(
    const float* __restrict__ outputs,   // [B, S]
    const float* __restrict__ hidden,    // [S, B, H]
    const float* __restrict__ W,         // [1, H]
    const float* __restrict__ bias,      // [1]
    float* __restrict__ out)             // [1 + P]: out[0]=loss, out[1+p]=pred
{
    const int lane = threadIdx.x & 63;
    const int sub  = lane >> 4;          // which of the 4 rows this lane serves
    const int l16  = lane & 15;          // lane within the 16-lane row group
    const int gwave  = (blockIdx.x * BLOCK + threadIdx.x) >> 6;
    const int nwaves = (GRID * BLOCK) >> 6;  // 8192

    // Lane owns W columns [l16*16, l16*16+16): 4 float4s, kept in registers.
    const float4* W4 = reinterpret_cast<const float4*>(W) + l16 * 4;
    const float4 w0 = W4[0], w1 = W4[1], w2 = W4[2], w3 = W4[3];
    const float b0 = bias[0];

    float se_acc = 0.0f;

    for (int base = gwave * 4; base < P; base += nwaves * 4) {
        const int p = base + sub;
        const float4* hp =
            reinterpret_cast<const float4*>(hidden + (size_t)p * H) + l16 * 4;
        const float4 h0 = hp[0], h1 = hp[1], h2 = hp[2], h3 = hp[3];

        float d = h0.x * w0.x + h0.y * w0.y + h0.z * w0.z + h0.w * w0.w;
        d += h1.x * w1.x + h1.y * w1.y + h1.z * w1.z + h1.w * w1.w;
        d += h2.x * w2.x + h2.y * w2.y + h2.z * w2.z + h2.w * w2.w;
        d += h3.x * w3.x + h3.y * w3.y + h3.z * w3.z + h3.w * w3.w;

        // Reduce across the 16-lane group (xor 1,2,4,8 stays within group).
        #pragma unroll
        for (int off = 1; off < 16; off <<= 1)
            d += __shfl_xor(d, off, 64);

        if (l16 == 0) {
            const float pred = d + b0;
            out[1 + p] = pred;
            const int s  = p >> 6;       // p = s*B + bb, B=64
            const int bb = p & 63;
            const float diff = pred - outputs[bb * S + s];
            se_acc += diff * diff;
        }
    }

    // Wave-level reduce of se_acc (non-leader lanes hold 0), then one
    // atomic per block.
    #pragma unroll
    for (int off = 32; off > 0; off >>= 1)
        se_acc += __shfl_xor(se_acc, off, 64);

    __shared__ float lsum[BLOCK / 64];
    if (lane == 0) lsum[threadIdx.x >> 6] = se_acc;
    __syncthreads();
    if (threadIdx.x == 0) {
        atomicAdd(out, lsum[0] + lsum[1] + lsum[2] + lsum[3]);
    }
}

extern "C" void kernel_launch(void* const* d_in, const int* in_sizes, int n_in,
                              void* d_out, int out_size, void* d_ws, size_t ws_size,
                              hipStream_t stream) {
    const float* outputs = (const float*)d_in[0];  // [B, S]
    const float* hidden  = (const float*)d_in[1];  // [S, B, H]
    const float* W       = (const float*)d_in[2];  // [1, H]
    const float* bias    = (const float*)d_in[3];  // [1]
    float* out = (float*)d_out;                    // [1 + S*B]

    // Atomic accumulator must start at 0 every call (harness doesn't re-poison).
    hipMemsetAsync(out, 0, sizeof(float), stream);

    decoder_kernel<<<GRID, BLOCK, 0, stream>>>(outputs, hidden, W, bias, out);
}